// Round 4
// baseline (573.462 us; speedup 1.0000x reference)
//
#include <hip/hip_runtime.h>
#include <math.h>

#define N_TOKENS 16384
#define D_MODEL  4096
#define NE       64
#define NC       128
#define DELTA    0.005f
#define LIST_CAP 16384

// ---- ws layout (bytes) ---- (proven: ws_size >= FAST_NEED)
#define WS_SUMS   0          // 128 f32
#define WS_CNT    512        // int
#define WS_LIST   4096       // 16384 int
#define WS_BHI    131072     // 1 MB bf16 hi limbs [128 kc][4 kg][128 n][8 j]
#define WS_BLO    1179648    // 1 MB bf16 lo limbs, same layout
#define FAST_NEED 2228224

typedef unsigned short u16;
typedef __attribute__((ext_vector_type(8))) short short8;   // 8 bf16
typedef __attribute__((ext_vector_type(4))) float f32x4;

#define MFMA16 __builtin_amdgcn_mfma_f32_16x16x32_bf16

typedef const __attribute__((address_space(1))) void cg_void;
typedef __attribute__((address_space(3))) void lds_void;
__device__ __forceinline__ void gll16(const void* g, void* l) {
    __builtin_amdgcn_global_load_lds((cg_void*)g, (lds_void*)l, 16, 0, 0);
}

#define WAITV(n) asm volatile("s_waitcnt vmcnt(" #n ")" ::: "memory")
#define SCHED0   __builtin_amdgcn_sched_barrier(0)

// raw global b128 load with immediate offset; vmcnt tracked manually.
#define GLD16(dst, ptr, off) \
    asm volatile("global_load_dwordx4 %0, %1, off offset:" #off \
                 : "=&v"(dst) : "v"(ptr) : "memory")

#define ISSUE_B8(a, p) do { \
    GLD16(a[0], p, 0);    GLD16(a[1], p, 256);  GLD16(a[2], p, 512);  GLD16(a[3], p, 768);  \
    GLD16(a[4], p, 1024); GLD16(a[5], p, 1280); GLD16(a[6], p, 1536); GLD16(a[7], p, 1792); \
} while (0)

__device__ __forceinline__ u16 f2bf(float x) {
    unsigned u = __float_as_uint(x);
    return (u16)((u + 0x7FFFu + ((u >> 16) & 1u)) >> 16);
}
__device__ __forceinline__ float bf2f(u16 h) { return __uint_as_float(((unsigned)h) << 16); }
__device__ __forceinline__ float softplus_f(float x) {
    return (x > 0.f) ? x + log1pf(expf(-x)) : log1pf(expf(x));
}
__device__ __forceinline__ float ncdf(float z) { return 0.5f * erfcf(-z * 0.70710678118654752f); }

// fp32x8 -> (hi, lo) bf16 limbs. Bit-identical to rounds 0-3:
// hi = trunc(u>>16), lo = f2bf(x - hi).
__device__ __forceinline__ void cvt8(const f32x4 a, const f32x4 b, short8& hi, short8& lo) {
    unsigned hu[8]; float rs[8];
    #pragma unroll
    for (int i = 0; i < 8; ++i) {
        const float x = (i < 4) ? a[i] : b[i - 4];
        const unsigned u = __float_as_uint(x);
        hu[i] = u;
        rs[i] = x - __uint_as_float(u & 0xFFFF0000u);
    }
    union { unsigned u[4]; short8 s; } H, L;
    #pragma unroll
    for (int i = 0; i < 4; ++i) {
        H.u[i] = (hu[2 * i] >> 16) | (hu[2 * i + 1] & 0xFFFF0000u);
        L.u[i] = (unsigned)f2bf(rs[2 * i]) | ((unsigned)f2bf(rs[2 * i + 1]) << 16);
    }
    hi = H.s; lo = L.s;
}

__global__ void k_zero(float* __restrict__ sums, int* __restrict__ cnt) {
    if (threadIdx.x < 128) sums[threadIdx.x] = 0.f;
    if (cnt != nullptr && threadIdx.x == 128) *cnt = 0;
}

// B limbs, k-major: elem offset = kc*4096 + kg*1024 + n*8 + j (k = kc*32 + kg*8 + j).
// 8KB per kc per limb; a wave's per-colblock frag read is a 1KB coalesced b128.
__global__ __launch_bounds__(256) void k_prep(const float* __restrict__ wg, const float* __restrict__ wn,
                                              u16* __restrict__ Bhi, u16* __restrict__ Blo) {
    __shared__ float sW[32 * 129];
    const int kc = blockIdx.x, tid = threadIdx.x;
    #pragma unroll
    for (int i = 0; i < 16; ++i) {
        const int v = tid + 256 * i;          // 4096 elems
        const int kk = v >> 7, n = v & 127;
        const int k = kc * 32 + kk;
        const float x = (n < 64) ? wg[(size_t)k * 64 + n] : wn[(size_t)k * 64 + n - 64];
        sW[kk * 129 + n] = x;
    }
    __syncthreads();
    #pragma unroll
    for (int i = 0; i < 16; ++i) {
        const int o   = tid + 256 * i;        // o = kg*1024 + n*8 + j
        const int kg  = o >> 10;
        const int rem = o & 1023;
        const int n   = rem >> 3, j = rem & 7;
        const int kk  = kg * 8 + j;
        const float x = sW[kk * 129 + n];
        const u16 h = f2bf(x);
        Bhi[(size_t)kc * 4096 + o] = h;
        Blo[(size_t)kc * 4096 + o] = f2bf(x - bf2f(h));
    }
}

// Round 4: BARRIER-FREE main loop. grid 256, block = 4 AUTONOMOUS waves (256 thr),
// wave tile = 16 tokens x 128 cols (acc 8x f32x4, 24 MFMA/chunk). Nothing shared
// between waves -> zero s_barrier in the K-loop (r0-r3 all ~204-235us across 4
// different schedules => the per-chunk barrier convoy is the prime suspect).
// B: global->reg, 16 b128/chunk (L1/L2-shared across waves). A: wave-private gll16
// ring-3 LDS (2KB slots), coalesced source with 8-position permutation so the
// ds_read_b128 is bank-conflict-free; per-wave counted vmcnt only.
// A LDS layout: row m (0..15), 16B-position p holds global position (p-m)&7;
// read chunk-k q*8..q*8+7 at positions (2q+m)&7, (2q+1+m)&7 -> 8 lanes/position.
__global__ __launch_bounds__(256, 1) void k_main(
    const float* __restrict__ inp, const u16* __restrict__ Bhi, const u16* __restrict__ Blo,
    const float* __restrict__ noise, float* __restrict__ out, float* __restrict__ sums,
    int* __restrict__ cnt, int* __restrict__ list)
{
    __shared__ __align__(16) char smem[53248];  // loop: 4 x 6144 A-ring; epi: 4 x 13312

    const int tid = threadIdx.x;
    const int l   = tid & 63;
    const int w   = tid >> 6;             // 0..3
    const int m   = l & 15;
    const int q   = l >> 4;               // k-group 0..3
    const int T0  = blockIdx.x * 64 + w * 16;   // wave's 16 tokens

    f32x4 acc[8];
    #pragma unroll
    for (int cf = 0; cf < 8; ++cf)
        #pragma unroll
        for (int r = 0; r < 4; ++r) acc[cf][r] = 0.f;

    // ---- A staging addresses ----
    char* const Ab    = smem + w * 6144;      // wave-private ring: 3 x 2048
    char* const AbEnd = Ab + 4096;
    const int m8 = l >> 3, p8 = l & 7;
    const int g8 = (p8 - m8) & 7;             // source position permutation
    const float* aS0 = inp + (size_t)(T0 + m8) * D_MODEL + g8 * 4;        // rows 0-7
    const float* aS1 = aS0 + 8 * D_MODEL;                                  // rows 8-15
    const int dsA0 = m * 128 + ((2 * q + m) & 7) * 16;
    const int dsA1 = m * 128 + ((2 * q + 1 + m) & 7) * 16;

    // ---- B frag pointers: per-lane base q*2048 + m*16; colblock cf at imm cf*256 ----
    const char* pBh = (const char*)Bhi + q * 2048 + m * 16;
    const char* pBl = (const char*)Blo + q * 2048 + m * 16;

    short8 bhA[8], blA[8], bhB[8], blB[8];

#define MFMA24(AH, AL, BH, BL) do { \
    _Pragma("unroll") \
    for (int cf = 0; cf < 8; ++cf) { \
        acc[cf] = MFMA16(AH, BH[cf], acc[cf], 0, 0, 0); \
        acc[cf] = MFMA16(AH, BL[cf], acc[cf], 0, 0, 0); \
        acc[cf] = MFMA16(AL, BH[cf], acc[cf], 0, 0, 0); \
    } \
} while (0)

    // ---- prologue: A(0)->slot0, B(0)->bankA, A(1)->slot1; drain A(0) ----
    gll16(aS0, Ab); gll16(aS1, Ab + 1024); aS0 += 32; aS1 += 32;
    ISSUE_B8(bhA, pBh); ISSUE_B8(blA, pBl); pBh += 8192; pBl += 8192;
    gll16(aS0, Ab + 2048); gll16(aS1, Ab + 2048 + 1024); aS0 += 32; aS1 += 32;
    WAITV(18); SCHED0;
    // invariant entering iter c: outstanding = [B(c):16, A(c+1):2]; A(c) in LDS slot c%3.

    char* rd = Ab;            // slot c%3
    char* wr = Ab + 4096;     // slot (c+2)%3

#define GSTEP(CURH, CURL, NXTH, NXTL) do { \
    const f32x4 fa0 = *(const f32x4*)(rd + dsA0); \
    const f32x4 fa1 = *(const f32x4*)(rd + dsA1); \
    ISSUE_B8(NXTH, pBh); ISSUE_B8(NXTL, pBl); pBh += 8192; pBl += 8192; \
    gll16(aS0, wr); gll16(aS1, wr + 1024); aS0 += 32; aS1 += 32; \
    WAITV(18); SCHED0; \
    short8 ah, al; cvt8(fa0, fa1, ah, al); \
    MFMA24(ah, al, CURH, CURL); \
    rd = (rd == AbEnd) ? Ab : rd + 2048; \
    wr = (wr == AbEnd) ? Ab : wr + 2048; \
} while (0)

    #pragma unroll 1
    for (int pc = 0; pc < 63; ++pc) {      // c = 0..125
        GSTEP(bhA, blA, bhB, blB);
        GSTEP(bhB, blB, bhA, blA);
    }
    {   // c = 126: issue B(127) only
        const f32x4 fa0 = *(const f32x4*)(rd + dsA0);
        const f32x4 fa1 = *(const f32x4*)(rd + dsA1);
        ISSUE_B8(bhB, pBh); ISSUE_B8(blB, pBl);
        WAITV(16); SCHED0;
        short8 ah, al; cvt8(fa0, fa1, ah, al);
        MFMA24(ah, al, bhA, blA);
        rd = (rd == AbEnd) ? Ab : rd + 2048;
    }
    {   // c = 127
        const f32x4 fa0 = *(const f32x4*)(rd + dsA0);
        const f32x4 fa1 = *(const f32x4*)(rd + dsA1);
        WAITV(0); SCHED0;
        short8 ah, al; cvt8(fa0, fa1, ah, al);
        MFMA24(ah, al, bhB, blB);
    }
#undef GSTEP
#undef MFMA24

    __syncthreads();   // ONLY barrier: A-ring region becomes epilogue overlay

    char* const E = smem + w * 13312;             // per-wave epilogue region
    float* const sL  = (float*)E;                 // [16][132] = 8448 B
    float* const sN  = (float*)(E + 8448);        // [16][68]  = 4352 B
    float* const sV1 = (float*)(E + 12800);
    float* const sV2 = (float*)(E + 12864);
    float* const sG0 = (float*)(E + 12928);
    float* const sG1 = (float*)(E + 12992);
    int*   const sI0 = (int*)(E + 13056);
    int*   const sI1 = (int*)(E + 13120);
    int*   const sRk = (int*)(E + 13184);

    // C/D layout (m89-verified): col = lane&15, row = (lane>>4)*4 + reg
    #pragma unroll
    for (int cf = 0; cf < 8; ++cf)
        #pragma unroll
        for (int r = 0; r < 4; ++r)
            sL[(q * 4 + r) * 132 + cf * 16 + m] = acc[cf][r];

    #pragma unroll
    for (int i = 0; i < 4; ++i) {                  // noise: 16 tok x 64 f32
        const int v = i * 64 + l;
        const int t = v >> 4, e4 = v & 15;
        *(float4*)&sN[t * 68 + e4 * 4] = *(const float4*)(noise + (size_t)(T0 + t) * NE + e4 * 4);
    }
    asm volatile("s_waitcnt lgkmcnt(0) vmcnt(0)" ::: "memory");
    SCHED0;

    if (l < 16) {
        const int t = l, gt = T0 + t;
        float v0 = -3.4e38f, v1 = -3.4e38f, v2 = -3.4e38f;
        int i0 = 0, i1 = 0;
        #pragma unroll 4
        for (int e = 0; e < NE; ++e) {
            const float clean = sL[t * 132 + e];
            const float sd    = softplus_f(sL[t * 132 + 64 + e]) + 0.01f;
            const float ny    = fmaf(sN[t * 68 + e], sd, clean);
            if (ny > v0)      { v2 = v1; v1 = v0; i1 = i0; v0 = ny; i0 = e; }
            else if (ny > v1) { v2 = v1; v1 = ny; i1 = e; }
            else if (ny > v2) { v2 = ny; }
        }
        const float e1 = expf(v1 - v0);
        const float d  = 1.f + e1;
        const float g0 = 1.f / d, g1 = e1 / d;
        out[2 * gt + 0] = (float)i0;
        out[2 * gt + 1] = (float)i1;
        out[2 * N_TOKENS + 2 * gt + 0] = g0;
        out[2 * N_TOKENS + 2 * gt + 1] = g1;
        const int risky = ((v0 - v1) < DELTA) || ((v1 - v2) < DELTA);
        sRk[t] = risky;
        if (risky) {
            const int idx = atomicAdd(cnt, 1);
            if (idx < LIST_CAP) list[idx] = gt;
        }
        sV1[t] = v1; sV2[t] = v2; sI0[t] = i0; sI1[t] = i1; sG0[t] = g0; sG1[t] = g1;
    }
    asm volatile("s_waitcnt lgkmcnt(0)" ::: "memory");
    SCHED0;

    {   // all 64 lanes: expert e = l, this wave's 16 tokens
        const int e = l;
        float loadsum = 0.f, impsum = 0.f;
        #pragma unroll 4
        for (int t = 0; t < 16; ++t) {
            if (sRk[t]) continue;
            const float clean = sL[t * 132 + e];
            const float sd    = softplus_f(sL[t * 132 + 64 + e]) + 0.01f;
            const float ny    = fmaf(sN[t * 68 + e], sd, clean);
            const float thr   = (ny > sV2[t]) ? sV2[t] : sV1[t];
            loadsum += ncdf((clean - thr) / sd);
            if (sI0[t] == e) impsum += sG0[t];
            if (sI1[t] == e) impsum += sG1[t];
        }
        atomicAdd(&sums[e], impsum);
        atomicAdd(&sums[64 + e], loadsum);
    }
}

// exact fp32 recompute for risky (near-tie) tokens; 512 thr, K split x4
__global__ __launch_bounds__(512) void k_fix(const float* __restrict__ inp,
                                             const float* __restrict__ wg,
                                             const float* __restrict__ wn,
                                             const float* __restrict__ noise,
                                             float* __restrict__ out,
                                             float* __restrict__ sums,
                                             const int* __restrict__ cnt,
                                             const int* __restrict__ list) {
    __shared__ float sRow[D_MODEL];
    __shared__ float sP[512];
    __shared__ float sLg[NC];
    __shared__ float fv1, fv2;

    const int tid = threadIdx.x;
    int n = *cnt;
    if (n > LIST_CAP) n = LIST_CAP;

    for (int it = blockIdx.x; it < n; it += gridDim.x) {
        const int tok = list[it];
        __syncthreads();
        #pragma unroll
        for (int i = 0; i < 2; ++i)
            *(float4*)&sRow[(tid + 512 * i) * 4] = *(const float4*)(inp + (size_t)tok * D_MODEL + (tid + 512 * i) * 4);
        __syncthreads();

        const int c = tid & 127, h = tid >> 7;
        const float* wcol = (c < 64) ? (wg + c) : (wn + c - 64);
        float s = 0.f;
        #pragma unroll 16
        for (int k = h * 1024; k < h * 1024 + 1024; ++k)
            s = fmaf(sRow[k], wcol[(size_t)k * 64], s);
        sP[tid] = s;
        __syncthreads();
        if (tid < 128) sLg[tid] = sP[tid] + sP[tid + 128] + sP[tid + 256] + sP[tid + 384];
        __syncthreads();

        if (tid == 0) {
            float v0 = -3.4e38f, v1 = -3.4e38f, v2 = -3.4e38f;
            int i0 = 0, i1 = 0;
            for (int e = 0; e < NE; ++e) {
                const float sd = softplus_f(sLg[64 + e]) + 0.01f;
                const float ny = fmaf(noise[(size_t)tok * NE + e], sd, sLg[e]);
                if (ny > v0)      { v2 = v1; v1 = v0; i1 = i0; v0 = ny; i0 = e; }
                else if (ny > v1) { v2 = v1; v1 = ny; i1 = e; }
                else if (ny > v2) { v2 = ny; }
            }
            const float e1 = expf(v1 - v0);
            const float d  = 1.f + e1;
            const float g0 = 1.f / d, g1 = e1 / d;
            out[2 * tok + 0] = (float)i0;
            out[2 * tok + 1] = (float)i1;
            out[2 * N_TOKENS + 2 * tok + 0] = g0;
            out[2 * N_TOKENS + 2 * tok + 1] = g1;
            atomicAdd(&sums[i0], g0);
            atomicAdd(&sums[i1], g1);
            fv1 = v1; fv2 = v2;
        }
        __syncthreads();
        if (tid < 64) {
            const int e = tid;
            const float clean = sLg[e];
            const float sd    = softplus_f(sLg[64 + e]) + 0.01f;
            const float ny    = fmaf(noise[(size_t)tok * NE + e], sd, clean);
            const float thr   = (ny > fv2) ? fv2 : fv1;
            atomicAdd(&sums[64 + e], ncdf((clean - thr) / sd));
        }
    }
}

__global__ void k_loss(const float* __restrict__ sums, float* __restrict__ out) {
    const int l = threadIdx.x;
    const float x = sums[l];
    const float y = sums[64 + l];
    float sx = x, sy = y;
    #pragma unroll
    for (int off = 32; off >= 1; off >>= 1) { sx += __shfl_xor(sx, off); sy += __shfl_xor(sy, off); }
    const float mx = sx / 64.f, my = sy / 64.f;
    const float dx = x - mx, dy = y - my;
    float vx = dx * dx, vy = dy * dy;
    #pragma unroll
    for (int off = 32; off >= 1; off >>= 1) { vx += __shfl_xor(vx, off); vy += __shfl_xor(vy, off); }
    if (l == 0)
        out[2 * N_TOKENS * 2] = (vx / 63.f) / (mx * mx + 1e-10f) + (vy / 63.f) / (my * my + 1e-10f);
}

// ---------- fallback: round-1 kernel, verbatim (uses only 512 B of ws) ----------
#define BT 32
#define BK 32
#define FBLOCK 256
__global__ __launch_bounds__(FBLOCK) void gate_fb(
    const float* __restrict__ inp, const float* __restrict__ w_gate,
    const float* __restrict__ w_noise, const float* __restrict__ noise,
    float* __restrict__ out, float* __restrict__ ws)
{
    __shared__ float sA[BT][BK + 1];
    __shared__ float sB[BK][NC];
    __shared__ float sL[BT][NC + 1];
    __shared__ float sN[BT][NE + 1];
    __shared__ float sV1[BT], sV2[BT], sG0[BT], sG1[BT];
    __shared__ int   sI0[BT], sI1[BT];

    const int tid = threadIdx.x;
    const int bt0 = blockIdx.x * BT;
    const int tc = tid & 15;
    const int tr = tid >> 4;

    float acc[2][8];
    #pragma unroll
    for (int i = 0; i < 2; ++i)
        #pragma unroll
        for (int j = 0; j < 8; ++j) acc[i][j] = 0.f;

    const int a_row = tid >> 3;
    const int a_c4  = tid & 7;

    for (int k0 = 0; k0 < D_MODEL; k0 += BK) {
        const float4 av = *(const float4*)(inp + (size_t)(bt0 + a_row) * D_MODEL + k0 + (a_c4 << 2));
        float4 bv[4];
        #pragma unroll
        for (int i = 0; i < 4; ++i) {
            const int v   = tid + (i << 8);
            const int row = v >> 5;
            const int c4  = v & 31;
            const float* src = (c4 < 16)
                ? (w_gate  + (size_t)(k0 + row) * NE + (c4 << 2))
                : (w_noise + (size_t)(k0 + row) * NE + ((c4 - 16) << 2));
            bv[i] = *(const float4*)src;
        }
        __syncthreads();
        sA[a_row][a_c4 * 4 + 0] = av.x;
        sA[a_row][a_c4 * 4 + 1] = av.y;
        sA[a_row][a_c4 * 4 + 2] = av.z;
        sA[a_row][a_c4 * 4 + 3] = av.w;
        #pragma unroll
        for (int i = 0; i < 4; ++i) {
            const int v   = tid + (i << 8);
            const int row = v >> 5;
            const int c4  = v & 31;
            *(float4*)&sB[row][c4 << 2] = bv[i];
        }
        __syncthreads();
        #pragma unroll
        for (int kk = 0; kk < BK; ++kk) {
            const float a0 = sA[tr * 2 + 0][kk];
            const float a1 = sA[tr * 2 + 1][kk];
            const float4 b0 = *(const float4*)&sB[kk][tc * 8 + 0];
            const float4 b1 = *(const float4*)&sB[kk][tc * 8 + 4];
            acc[0][0] = fmaf(a0, b0.x, acc[0][0]); acc[0][1] = fmaf(a0, b0.y, acc[0][1]);
            acc[0][2] = fmaf(a0, b0.z, acc[0][2]); acc[0][3] = fmaf(a0, b0.w, acc[0][3]);
            acc[0][4] = fmaf(a0, b1.x, acc[0][4]); acc[0][5] = fmaf(a0, b1.y, acc[0][5]);
            acc[0][6] = fmaf(a0, b1.z, acc[0][6]); acc[0][7] = fmaf(a0, b1.w, acc[0][7]);
            acc[1][0] = fmaf(a1, b0.x, acc[1][0]); acc[1][1] = fmaf(a1, b0.y, acc[1][1]);
            acc[1][2] = fmaf(a1, b0.z, acc[1][2]); acc[1][3] = fmaf(a1, b0.w, acc[1][3]);
            acc[1][4] = fmaf(a1, b1.x, acc[1][4]); acc[1][5] = fmaf(a1, b1.y, acc[1][5]);
            acc[1][6] = fmaf(a1, b1.z, acc[1][6]); acc[1][7] = fmaf(a1, b1.w, acc[1][7]);
        }
    }

    __syncthreads();
    #pragma unroll
    for (int i = 0; i < 2; ++i)
        #pragma unroll
        for (int j = 0; j < 8; ++j)
            sL[tr * 2 + i][tc * 8 + j] = acc[i][j];

    for (int v = tid; v < BT * NE; v += FBLOCK) {
        const int t = v >> 6, e = v & 63;
        sN[t][e] = noise[(size_t)(bt0 + t) * NE + e];
    }
    __syncthreads();

    if (tid < BT) {
        const int t  = tid;
        const int gt = bt0 + t;
        float v0 = -3.4e38f, v1 = -3.4e38f, v2 = -3.4e38f;
        int   i0 = 0, i1 = 0;
        #pragma unroll 4
        for (int e = 0; e < NE; ++e) {
            const float clean = sL[t][e];
            const float raw   = sL[t][NE + e];
            const float sd    = softplus_f(raw) + 0.01f;
            sL[t][NE + e] = sd;
            const float ny = fmaf(sN[t][e], sd, clean);
            sN[t][e] = ny;
            if (ny > v0)      { v2 = v1; v1 = v0; i1 = i0; v0 = ny; i0 = e; }
            else if (ny > v1) { v2 = v1; v1 = ny; i1 = e; }
            else if (ny > v2) { v2 = ny; }
        }
        const float e1 = expf(v1 - v0);
        const float d  = 1.f + e1;
        const float g0 = 1.f / d;
        const float g1 = e1 / d;
        out[2 * gt + 0] = (float)i0;
        out[2 * gt + 1] = (float)i1;
        out[2 * N_TOKENS + 2 * gt + 0] = g0;
        out[2 * N_TOKENS + 2 * gt + 1] = g1;
        sV1[t] = v1; sV2[t] = v2;
        sI0[t] = i0; sI1[t] = i1;
        sG0[t] = g0; sG1[t] = g1;
    }
    __syncthreads();

    if (tid < NE) {
        const int e = tid;
        float loadsum = 0.f, impsum = 0.f;
        #pragma unroll 4
        for (int t = 0; t < BT; ++t) {
            const float clean = sL[t][e];
            const float sd    = sL[t][NE + e];
            const float ny    = sN[t][e];
            const float thr   = (ny > sV2[t]) ? sV2[t] : sV1[t];
            const float z     = (clean - thr) / sd;
            loadsum += ncdf(z);
            if (sI0[t] == e) impsum += sG0[t];
            if (sI1[t] == e) impsum += sG1[t];
        }
        atomicAdd(&ws[e],      impsum);
        atomicAdd(&ws[NE + e], loadsum);
    }
}

extern "C" void kernel_launch(void* const* d_in, const int* in_sizes, int n_in,
                              void* d_out, int out_size, void* d_ws, size_t ws_size,
                              hipStream_t stream) {
    const float* inp     = (const float*)d_in[0];
    const float* w_gate  = (const float*)d_in[1];
    const float* w_noise = (const float*)d_in[2];
    const float* noise   = (const float*)d_in[3];
    float* out = (float*)d_out;

    float* sums = (float*)((char*)d_ws + WS_SUMS);
    int*   cnt  = (int*)((char*)d_ws + WS_CNT);
    int*   list = (int*)((char*)d_ws + WS_LIST);
    u16*   Bhi  = (u16*)((char*)d_ws + WS_BHI);
    u16*   Blo  = (u16*)((char*)d_ws + WS_BLO);

    if (ws_size >= (size_t)FAST_NEED) {
        k_zero<<<1, 192, 0, stream>>>(sums, cnt);
        k_prep<<<128, 256, 0, stream>>>(w_gate, w_noise, Bhi, Blo);
        k_main<<<N_TOKENS / 64, 256, 0, stream>>>(inp, Bhi, Blo, noise, out, sums, cnt, list);
        k_fix<<<1024, 512, 0, stream>>>(inp, w_gate, w_noise, noise, out, sums, cnt, list);
        k_loss<<<1, 64, 0, stream>>>(sums, out);
    } else {
        k_zero<<<1, 192, 0, stream>>>(sums, nullptr);
        gate_fb<<<N_TOKENS / BT, FBLOCK, 0, stream>>>(inp, w_gate, w_noise, noise, out, sums);
        k_loss<<<1, 64, 0, stream>>>(sums, out);
    }
}

// Round 5
// 534.382 us; speedup vs baseline: 1.0731x; 1.0731x over previous
//
#include <hip/hip_runtime.h>
#include <math.h>

#define N_TOKENS 16384
#define D_MODEL  4096
#define NE       64
#define NC       128
#define DELTA    0.005f
#define LIST_CAP 16384

// ---- ws layout (bytes) ---- (proven: ws_size >= FAST_NEED)
#define WS_SUMS   0          // 128 f32
#define WS_CNT    512        // int
#define WS_LIST   4096       // 16384 int
#define WS_BHI    131072     // 1 MB bf16 hi limbs [128 kc][4 kg][128 n][8 j]
#define WS_BLO    1179648    // 1 MB bf16 lo limbs, same layout
#define FAST_NEED 2228224

// k_main LDS map (dynamic, 147456 B): B ring-6 x 16KB @0 (hi 8K + lo 8K per slot);
// A ring-6 x 8KB @98304 (fp32, 64 rows x 8 rotated 16B units per row).
#define BBASE 0
#define ABASE 98304
#define LDS_MAIN 147456

typedef unsigned short u16;
typedef __attribute__((ext_vector_type(8))) short short8;   // 8 bf16
typedef __attribute__((ext_vector_type(4))) float f32x4;

#define MFMA16 __builtin_amdgcn_mfma_f32_16x16x32_bf16

typedef const __attribute__((address_space(1))) void cg_void;
typedef __attribute__((address_space(3))) void lds_void;
__device__ __forceinline__ void gll16(const void* g, void* l) {
    __builtin_amdgcn_global_load_lds((cg_void*)g, (lds_void*)l, 16, 0, 0);
}

#define WAITV(n) asm volatile("s_waitcnt vmcnt(" #n ")" ::: "memory")

__device__ __forceinline__ u16 f2bf(float x) {
    unsigned u = __float_as_uint(x);
    return (u16)((u + 0x7FFFu + ((u >> 16) & 1u)) >> 16);
}
__device__ __forceinline__ float bf2f(u16 h) { return __uint_as_float(((unsigned)h) << 16); }
__device__ __forceinline__ float softplus_f(float x) {
    return (x > 0.f) ? x + log1pf(expf(-x)) : log1pf(expf(x));
}
__device__ __forceinline__ float ncdf(float z) { return 0.5f * erfcf(-z * 0.70710678118654752f); }

// fp32x8 -> (hi, lo) bf16 limbs. Bit-identical to rounds 0-4:
// hi = trunc(u>>16), lo = f2bf(x - hi).
__device__ __forceinline__ void cvt8(const f32x4 a, const f32x4 b, short8& hi, short8& lo) {
    unsigned hu[8]; float rs[8];
    #pragma unroll
    for (int i = 0; i < 8; ++i) {
        const float x = (i < 4) ? a[i] : b[i - 4];
        const unsigned u = __float_as_uint(x);
        hu[i] = u;
        rs[i] = x - __uint_as_float(u & 0xFFFF0000u);
    }
    union { unsigned u[4]; short8 s; } H, L;
    #pragma unroll
    for (int i = 0; i < 4; ++i) {
        H.u[i] = (hu[2 * i] >> 16) | (hu[2 * i + 1] & 0xFFFF0000u);
        L.u[i] = (unsigned)f2bf(rs[2 * i]) | ((unsigned)f2bf(rs[2 * i + 1]) << 16);
    }
    hi = H.s; lo = L.s;
}

__global__ void k_zero(float* __restrict__ sums, int* __restrict__ cnt) {
    if (threadIdx.x < 128) sums[threadIdx.x] = 0.f;
    if (cnt != nullptr && threadIdx.x == 128) *cnt = 0;
}

// B limbs, k-major: elem offset = kc*4096 + kg*1024 + n*8 + j (k = kc*32 + kg*8 + j).
// 8KB per kc per limb, linear in gll16 lane order.
__global__ __launch_bounds__(256) void k_prep(const float* __restrict__ wg, const float* __restrict__ wn,
                                              u16* __restrict__ Bhi, u16* __restrict__ Blo) {
    __shared__ float sW[32 * 129];
    const int kc = blockIdx.x, tid = threadIdx.x;
    #pragma unroll
    for (int i = 0; i < 16; ++i) {
        const int v = tid + 256 * i;          // 4096 elems
        const int kk = v >> 7, n = v & 127;
        const int k = kc * 32 + kk;
        const float x = (n < 64) ? wg[(size_t)k * 64 + n] : wn[(size_t)k * 64 + n - 64];
        sW[kk * 129 + n] = x;
    }
    __syncthreads();
    #pragma unroll
    for (int i = 0; i < 16; ++i) {
        const int o   = tid + 256 * i;        // o = kg*1024 + n*8 + j
        const int kg  = o >> 10;
        const int rem = o & 1023;
        const int n   = rem >> 3, j = rem & 7;
        const int kk  = kg * 8 + j;
        const float x = sW[kk * 129 + n];
        const u16 h = f2bf(x);
        Bhi[(size_t)kc * 4096 + o] = h;
        Blo[(size_t)kc * 4096 + o] = f2bf(x - bf2f(h));
    }
}

// Round 5: PRODUCER/CONSUMER wave specialization (decoupled vmcnt queues).
// grid 256, block 768 = 12 waves: waves 0-7 consumers (64 tok x 128 col, wave tile
// 16x64, 12 MFMA/chunk), waves 8-11 producers (all vmem). Producers keep 5 chunks
// (120KB/CU) of gll16 in flight on THEIR vmcnt; consumers do zero vmem in the loop
// so their __syncthreads vmcnt(0) is free. Rings: B ring-6 16KB slots, A ring-6
// 8KB fp32 slots (rotated 16B units per row -> quarter-wave 2-way reads = free).
// Limbs converted in-register at read (cvt8) -- bit-identical to rounds 0-4.
__global__ __launch_bounds__(768, 1) void k_main(
    const float* __restrict__ inp, const u16* __restrict__ Bhi, const u16* __restrict__ Blo,
    const float* __restrict__ noise, float* __restrict__ out, float* __restrict__ sums,
    int* __restrict__ cnt, int* __restrict__ list)
{
    extern __shared__ __align__(16) char smem[];

    const int tid = threadIdx.x;
    const int l   = tid & 63;
    const int w   = tid >> 6;             // 0..11
    const int T0  = blockIdx.x * 64;
    const int m   = l & 15;
    const int q   = l >> 4;               // 0..3
    const int r0  = (w & 3) * 16;         // consumer row base
    const int c0  = (w >> 2) * 64;        // consumer col base (waves 0-3: 0, 4-7: 64)

    f32x4 acc[4];
    #pragma unroll
    for (int cf = 0; cf < 4; ++cf)
        #pragma unroll
        for (int r = 0; r < 4; ++r) acc[cf][r] = 0.f;

    if (w < 8) {
        // ================= consumers =================
        const int R    = r0 + m;
        const int aro0 = R * 128 + ((2 * q + R) & 7) * 16;
        const int aro1 = R * 128 + ((2 * q + 1 + R) & 7) * 16;
        const int bfo  = q * 2048 + (c0 + m) * 16;

        __syncthreads();                  // pairs with producer prologue barrier
        int s = 0;
        #pragma unroll 1
        for (int c = 0; c < 128; ++c) {
            const char* Bb = smem + BBASE + s * 16384;
            const char* Aa = smem + ABASE + s * 8192;
            const f32x4 fa0 = *(const f32x4*)(Aa + aro0);
            const f32x4 fa1 = *(const f32x4*)(Aa + aro1);
            short8 ah, al8; cvt8(fa0, fa1, ah, al8);
            short8 bh[4], bl[4];
            #pragma unroll
            for (int cf = 0; cf < 4; ++cf) {
                bh[cf] = *(const short8*)(Bb + bfo + cf * 256);
                bl[cf] = *(const short8*)(Bb + 8192 + bfo + cf * 256);
            }
            __builtin_amdgcn_s_setprio(1);
            #pragma unroll
            for (int cf = 0; cf < 4; ++cf) {
                acc[cf] = MFMA16(ah,  bh[cf], acc[cf], 0, 0, 0);
                acc[cf] = MFMA16(ah,  bl[cf], acc[cf], 0, 0, 0);
                acc[cf] = MFMA16(al8, bh[cf], acc[cf], 0, 0, 0);
            }
            __builtin_amdgcn_s_setprio(0);
            s = (s == 5) ? 0 : s + 1;
            __syncthreads();              // consumers' vmcnt is 0 -> drain is free
        }
    } else {
        // ================= producers =================
        const int pw  = w - 8;            // 0..3
        const int sgB = 2 * pw;           // this wave's two 1KB segments (B and A)
        // A source (fp32, rotated): seg j covers rows j*8..j*8+7; lane l -> row
        // rj = j*8 + (l>>3), holds 16B unit u=(l&7) = global unit (u - rj) & 7.
        const int rj0 = sgB * 8 + (l >> 3);
        const int g80 = (((l & 7) - (l >> 3)) & 7);
        const float* aSrc0 = inp + (size_t)(T0 + rj0) * D_MODEL + g80 * 4;
        const float* aSrc1 = aSrc0 + 8 * D_MODEL;
        const char* bhSrc = (const char*)Bhi + sgB * 1024 + l * 16;
        const char* blSrc = (const char*)Blo + sgB * 1024 + l * 16;

        auto pissue = [&](const int cc, const int sl) {   // 6 gll16 (6KB of 24KB/chunk)
            char* bb = smem + BBASE + sl * 16384;
            char* ab = smem + ABASE + sl * 8192;
            const size_t bo = (size_t)cc * 8192;
            gll16(bhSrc + bo,        bb + sgB * 1024);
            gll16(bhSrc + bo + 1024, bb + sgB * 1024 + 1024);
            gll16(blSrc + bo,        bb + 8192 + sgB * 1024);
            gll16(blSrc + bo + 1024, bb + 8192 + sgB * 1024 + 1024);
            gll16(aSrc0 + cc * 32, ab + sgB * 1024);
            gll16(aSrc1 + cc * 32, ab + sgB * 1024 + 1024);
        };

        // prologue: chunks 0..4 in flight (30 calls); drain chunk 0; release consumers.
        #pragma unroll 1
        for (int cc = 0; cc < 5; ++cc) pissue(cc, cc);
        WAITV(24);
        __builtin_amdgcn_s_barrier();

        int sp = 5;                       // slot for chunk c+5
        #pragma unroll 1
        for (int c = 0; c < 128; ++c) {
            if (c <= 122) {
                pissue(c + 5, sp);        // up to 30 outstanding on THIS wave only
                sp = (sp == 5) ? 0 : sp + 1;
                WAITV(24);                // drain chunk c+1's 6 calls
            } else if (c == 123) { WAITV(18); }
            else if (c == 124)   { WAITV(12); }
            else if (c == 125)   { WAITV(6); }
            else if (c == 126)   { WAITV(0); }
            __builtin_amdgcn_s_barrier();
        }
    }

    __syncthreads();   // GEMM LDS dead; overlay epilogue arrays

    float* const sL  = (float*)(smem);            // [64][132] = 33792 B
    float* const sN  = (float*)(smem + 33792);    // [64][68]  = 17408 B
    float* const sV1 = (float*)(smem + 51200);
    float* const sV2 = (float*)(smem + 51456);
    float* const sG0 = (float*)(smem + 51712);
    float* const sG1 = (float*)(smem + 51968);
    int*   const sI0 = (int*)(smem + 52224);
    int*   const sI1 = (int*)(smem + 52480);
    int*   const sRk = (int*)(smem + 52736);

    // C/D layout (m89-verified): col = lane&15, row = (lane>>4)*4 + reg
    if (w < 8) {
        #pragma unroll
        for (int cf = 0; cf < 4; ++cf)
            #pragma unroll
            for (int r = 0; r < 4; ++r)
                sL[(r0 + q * 4 + r) * 132 + c0 + cf * 16 + m] = acc[cf][r];
    }
    if (tid < 512) {   // noise: 64x64 = 1024 float4, two per thread
        #pragma unroll
        for (int i = 0; i < 2; ++i) {
            const int v = tid + 512 * i;
            const int t = v >> 4, e4 = v & 15;
            *(float4*)&sN[t * 68 + e4 * 4] = *(const float4*)(noise + (size_t)(T0 + t) * NE + e4 * 4);
        }
    }
    __syncthreads();

    if (tid < 64) {
        const int t = tid, gt = T0 + t;
        float v0 = -3.4e38f, v1 = -3.4e38f, v2 = -3.4e38f;
        int i0 = 0, i1 = 0;
        #pragma unroll 4
        for (int e = 0; e < NE; ++e) {
            const float clean = sL[t * 132 + e];
            const float sd    = softplus_f(sL[t * 132 + 64 + e]) + 0.01f;
            const float ny    = fmaf(sN[t * 68 + e], sd, clean);
            if (ny > v0)      { v2 = v1; v1 = v0; i1 = i0; v0 = ny; i0 = e; }
            else if (ny > v1) { v2 = v1; v1 = ny; i1 = e; }
            else if (ny > v2) { v2 = ny; }
        }
        const float e1 = expf(v1 - v0);
        const float d  = 1.f + e1;
        const float g0 = 1.f / d, g1 = e1 / d;
        out[2 * gt + 0] = (float)i0;
        out[2 * gt + 1] = (float)i1;
        out[2 * N_TOKENS + 2 * gt + 0] = g0;
        out[2 * N_TOKENS + 2 * gt + 1] = g1;
        const int risky = ((v0 - v1) < DELTA) || ((v1 - v2) < DELTA);
        sRk[t] = risky;
        if (risky) {
            const int idx = atomicAdd(cnt, 1);
            if (idx < LIST_CAP) list[idx] = gt;
        }
        sV1[t] = v1; sV2[t] = v2; sI0[t] = i0; sI1[t] = i1; sG0[t] = g0; sG1[t] = g1;
    }
    __syncthreads();

    if (tid < 256) {
        const int e = tid & 63, h = tid >> 6;
        float loadsum = 0.f, impsum = 0.f;
        #pragma unroll 4
        for (int t = h * 16; t < h * 16 + 16; ++t) {
            if (sRk[t]) continue;
            const float clean = sL[t * 132 + e];
            const float sd    = softplus_f(sL[t * 132 + 64 + e]) + 0.01f;
            const float ny    = fmaf(sN[t * 68 + e], sd, clean);
            const float thr   = (ny > sV2[t]) ? sV2[t] : sV1[t];
            loadsum += ncdf((clean - thr) / sd);
            if (sI0[t] == e) impsum += sG0[t];
            if (sI1[t] == e) impsum += sG1[t];
        }
        atomicAdd(&sums[e], impsum);
        atomicAdd(&sums[64 + e], loadsum);
    }
}

// exact fp32 recompute for risky (near-tie) tokens; 512 thr, K split x4
__global__ __launch_bounds__(512) void k_fix(const float* __restrict__ inp,
                                             const float* __restrict__ wg,
                                             const float* __restrict__ wn,
                                             const float* __restrict__ noise,
                                             float* __restrict__ out,
                                             float* __restrict__ sums,
                                             const int* __restrict__ cnt,
                                             const int* __restrict__ list) {
    __shared__ float sRow[D_MODEL];
    __shared__ float sP[512];
    __shared__ float sLg[NC];
    __shared__ float fv1, fv2;

    const int tid = threadIdx.x;
    int n = *cnt;
    if (n > LIST_CAP) n = LIST_CAP;

    for (int it = blockIdx.x; it < n; it += gridDim.x) {
        const int tok = list[it];
        __syncthreads();
        #pragma unroll
        for (int i = 0; i < 2; ++i)
            *(float4*)&sRow[(tid + 512 * i) * 4] = *(const float4*)(inp + (size_t)tok * D_MODEL + (tid + 512 * i) * 4);
        __syncthreads();

        const int c = tid & 127, h = tid >> 7;
        const float* wcol = (c < 64) ? (wg + c) : (wn + c - 64);
        float s = 0.f;
        #pragma unroll 16
        for (int k = h * 1024; k < h * 1024 + 1024; ++k)
            s = fmaf(sRow[k], wcol[(size_t)k * 64], s);
        sP[tid] = s;
        __syncthreads();
        if (tid < 128) sLg[tid] = sP[tid] + sP[tid + 128] + sP[tid + 256] + sP[tid + 384];
        __syncthreads();

        if (tid == 0) {
            float v0 = -3.4e38f, v1 = -3.4e38f, v2 = -3.4e38f;
            int i0 = 0, i1 = 0;
            for (int e = 0; e < NE; ++e) {
                const float sd = softplus_f(sLg[64 + e]) + 0.01f;
                const float ny = fmaf(noise[(size_t)tok * NE + e], sd, sLg[e]);
                if (ny > v0)      { v2 = v1; v1 = v0; i1 = i0; v0 = ny; i0 = e; }
                else if (ny > v1) { v2 = v1; v1 = ny; i1 = e; }
                else if (ny > v2) { v2 = ny; }
            }
            const float e1 = expf(v1 - v0);
            const float d  = 1.f + e1;
            const float g0 = 1.f / d, g1 = e1 / d;
            out[2 * tok + 0] = (float)i0;
            out[2 * tok + 1] = (float)i1;
            out[2 * N_TOKENS + 2 * tok + 0] = g0;
            out[2 * N_TOKENS + 2 * tok + 1] = g1;
            atomicAdd(&sums[i0], g0);
            atomicAdd(&sums[i1], g1);
            fv1 = v1; fv2 = v2;
        }
        __syncthreads();
        if (tid < 64) {
            const int e = tid;
            const float clean = sLg[e];
            const float sd    = softplus_f(sLg[64 + e]) + 0.01f;
            const float ny    = fmaf(noise[(size_t)tok * NE + e], sd, clean);
            const float thr   = (ny > fv2) ? fv2 : fv1;
            atomicAdd(&sums[64 + e], ncdf((clean - thr) / sd));
        }
    }
}

__global__ void k_loss(const float* __restrict__ sums, float* __restrict__ out) {
    const int l = threadIdx.x;
    const float x = sums[l];
    const float y = sums[64 + l];
    float sx = x, sy = y;
    #pragma unroll
    for (int off = 32; off >= 1; off >>= 1) { sx += __shfl_xor(sx, off); sy += __shfl_xor(sy, off); }
    const float mx = sx / 64.f, my = sy / 64.f;
    const float dx = x - mx, dy = y - my;
    float vx = dx * dx, vy = dy * dy;
    #pragma unroll
    for (int off = 32; off >= 1; off >>= 1) { vx += __shfl_xor(vx, off); vy += __shfl_xor(vy, off); }
    if (l == 0)
        out[2 * N_TOKENS * 2] = (vx / 63.f) / (mx * mx + 1e-10f) + (vy / 63.f) / (my * my + 1e-10f);
}

// ---------- fallback: round-1 kernel, verbatim (uses only 512 B of ws) ----------
#define BT 32
#define BK 32
#define FBLOCK 256
__global__ __launch_bounds__(FBLOCK) void gate_fb(
    const float* __restrict__ inp, const float* __restrict__ w_gate,
    const float* __restrict__ w_noise, const float* __restrict__ noise,
    float* __restrict__ out, float* __restrict__ ws)
{
    __shared__ float sA[BT][BK + 1];
    __shared__ float sB[BK][NC];
    __shared__ float sL[BT][NC + 1];
    __shared__ float sN[BT][NE + 1];
    __shared__ float sV1[BT], sV2[BT], sG0[BT], sG1[BT];
    __shared__ int   sI0[BT], sI1[BT];

    const int tid = threadIdx.x;
    const int bt0 = blockIdx.x * BT;
    const int tc = tid & 15;
    const int tr = tid >> 4;

    float acc[2][8];
    #pragma unroll
    for (int i = 0; i < 2; ++i)
        #pragma unroll
        for (int j = 0; j < 8; ++j) acc[i][j] = 0.f;

    const int a_row = tid >> 3;
    const int a_c4  = tid & 7;

    for (int k0 = 0; k0 < D_MODEL; k0 += BK) {
        const float4 av = *(const float4*)(inp + (size_t)(bt0 + a_row) * D_MODEL + k0 + (a_c4 << 2));
        float4 bv[4];
        #pragma unroll
        for (int i = 0; i < 4; ++i) {
            const int v   = tid + (i << 8);
            const int row = v >> 5;
            const int c4  = v & 31;
            const float* src = (c4 < 16)
                ? (w_gate  + (size_t)(k0 + row) * NE + (c4 << 2))
                : (w_noise + (size_t)(k0 + row) * NE + ((c4 - 16) << 2));
            bv[i] = *(const float4*)src;
        }
        __syncthreads();
        sA[a_row][a_c4 * 4 + 0] = av.x;
        sA[a_row][a_c4 * 4 + 1] = av.y;
        sA[a_row][a_c4 * 4 + 2] = av.z;
        sA[a_row][a_c4 * 4 + 3] = av.w;
        #pragma unroll
        for (int i = 0; i < 4; ++i) {
            const int v   = tid + (i << 8);
            const int row = v >> 5;
            const int c4  = v & 31;
            *(float4*)&sB[row][c4 << 2] = bv[i];
        }
        __syncthreads();
        #pragma unroll
        for (int kk = 0; kk < BK; ++kk) {
            const float a0 = sA[tr * 2 + 0][kk];
            const float a1 = sA[tr * 2 + 1][kk];
            const float4 b0 = *(const float4*)&sB[kk][tc * 8 + 0];
            const float4 b1 = *(const float4*)&sB[kk][tc * 8 + 4];
            acc[0][0] = fmaf(a0, b0.x, acc[0][0]); acc[0][1] = fmaf(a0, b0.y, acc[0][1]);
            acc[0][2] = fmaf(a0, b0.z, acc[0][2]); acc[0][3] = fmaf(a0, b0.w, acc[0][3]);
            acc[0][4] = fmaf(a0, b1.x, acc[0][4]); acc[0][5] = fmaf(a0, b1.y, acc[0][5]);
            acc[0][6] = fmaf(a0, b1.z, acc[0][6]); acc[0][7] = fmaf(a0, b1.w, acc[0][7]);
            acc[1][0] = fmaf(a1, b0.x, acc[1][0]); acc[1][1] = fmaf(a1, b0.y, acc[1][1]);
            acc[1][2] = fmaf(a1, b0.z, acc[1][2]); acc[1][3] = fmaf(a1, b0.w, acc[1][3]);
            acc[1][4] = fmaf(a1, b1.x, acc[1][4]); acc[1][5] = fmaf(a1, b1.y, acc[1][5]);
            acc[1][6] = fmaf(a1, b1.z, acc[1][6]); acc[1][7] = fmaf(a1, b1.w, acc[1][7]);
        }
    }

    __syncthreads();
    #pragma unroll
    for (int i = 0; i < 2; ++i)
        #pragma unroll
        for (int j = 0; j < 8; ++j)
            sL[tr * 2 + i][tc * 8 + j] = acc[i][j];

    for (int v = tid; v < BT * NE; v += FBLOCK) {
        const int t = v >> 6, e = v & 63;
        sN[t][e] = noise[(size_t)(bt0 + t) * NE + e];
    }
    __syncthreads();

    if (tid < BT) {
        const int t  = tid;
        const int gt = bt0 + t;
        float v0 = -3.4e38f, v1 = -3.4e38f, v2 = -3.4e38f;
        int   i0 = 0, i1 = 0;
        #pragma unroll 4
        for (int e = 0; e < NE; ++e) {
            const float clean = sL[t][e];
            const float raw   = sL[t][NE + e];
            const float sd    = softplus_f(raw) + 0.01f;
            sL[t][NE + e] = sd;
            const float ny = fmaf(sN[t][e], sd, clean);
            sN[t][e] = ny;
            if (ny > v0)      { v2 = v1; v1 = v0; i1 = i0; v0 = ny; i0 = e; }
            else if (ny > v1) { v2 = v1; v1 = ny; i1 = e; }
            else if (ny > v2) { v2 = ny; }
        }
        const float e1 = expf(v1 - v0);
        const float d  = 1.f + e1;
        const float g0 = 1.f / d;
        const float g1 = e1 / d;
        out[2 * gt + 0] = (float)i0;
        out[2 * gt + 1] = (float)i1;
        out[2 * N_TOKENS + 2 * gt + 0] = g0;
        out[2 * N_TOKENS + 2 * gt + 1] = g1;
        sV1[t] = v1; sV2[t] = v2;
        sI0[t] = i0; sI1[t] = i1;
        sG0[t] = g0; sG1[t] = g1;
    }
    __syncthreads();

    if (tid < NE) {
        const int e = tid;
        float loadsum = 0.f, impsum = 0.f;
        #pragma unroll 4
        for (int t = 0; t < BT; ++t) {
            const float clean = sL[t][e];
            const float sd    = sL[t][NE + e];
            const float ny    = sN[t][e];
            const float thr   = (ny > sV2[t]) ? sV2[t] : sV1[t];
            const float z     = (clean - thr) / sd;
            loadsum += ncdf(z);
            if (sI0[t] == e) impsum += sG0[t];
            if (sI1[t] == e) impsum += sG1[t];
        }
        atomicAdd(&ws[e],      impsum);
        atomicAdd(&ws[NE + e], loadsum);
    }
}

extern "C" void kernel_launch(void* const* d_in, const int* in_sizes, int n_in,
                              void* d_out, int out_size, void* d_ws, size_t ws_size,
                              hipStream_t stream) {
    const float* inp     = (const float*)d_in[0];
    const float* w_gate  = (const float*)d_in[1];
    const float* w_noise = (const float*)d_in[2];
    const float* noise   = (const float*)d_in[3];
    float* out = (float*)d_out;

    float* sums = (float*)((char*)d_ws + WS_SUMS);
    int*   cnt  = (int*)((char*)d_ws + WS_CNT);
    int*   list = (int*)((char*)d_ws + WS_LIST);
    u16*   Bhi  = (u16*)((char*)d_ws + WS_BHI);
    u16*   Blo  = (u16*)((char*)d_ws + WS_BLO);

    // one-time: raise dynamic-LDS cap for k_main (not a stream op; graph-safe)
    static int attr_ok = -1;
    if (attr_ok < 0)
        attr_ok = (hipFuncSetAttribute((const void*)k_main,
                    hipFuncAttributeMaxDynamicSharedMemorySize, LDS_MAIN) == hipSuccess) ? 1 : 0;

    if (ws_size >= (size_t)FAST_NEED && attr_ok == 1) {
        k_zero<<<1, 192, 0, stream>>>(sums, cnt);
        k_prep<<<128, 256, 0, stream>>>(w_gate, w_noise, Bhi, Blo);
        k_main<<<N_TOKENS / 64, 768, LDS_MAIN, stream>>>(inp, Bhi, Blo, noise, out, sums, cnt, list);
        k_fix<<<2048, 512, 0, stream>>>(inp, w_gate, w_noise, noise, out, sums, cnt, list);
        k_loss<<<1, 64, 0, stream>>>(sums, out);
    } else {
        k_zero<<<1, 192, 0, stream>>>(sums, nullptr);
        gate_fb<<<N_TOKENS / BT, FBLOCK, 0, stream>>>(inp, w_gate, w_noise, noise, out, sums);
        k_loss<<<1, 64, 0, stream>>>(sums, out);
    }
}